// Round 20
// baseline (512.869 us; speedup 1.0000x reference)
//
#include <hip/hip_runtime.h>
#include <hip/hip_bf16.h>

// Problem constants (match reference)
#define B_GR   128
#define GWID   30
#define IWID   90
#define C_IN   32
#define R_REL  8
#define NBAS   4
#define N_NODES (B_GR*GWID*GWID)   // 115200
#define E_EDGES (N_NODES*8)        // 921600
#define NEG_SLOPE 0.01f

#define SCAN_BLOCKS (N_NODES/256)  // 450

typedef __attribute__((ext_vector_type(8))) __bf16 bf16x8;
typedef __attribute__((ext_vector_type(4))) float f32x4;

// ======================================================================
// Weight prep: Bt[b][c][k] = bf16(bases[b][k][c])  (B^T per base)
//              loopt[c][k] = bf16(loopw[k][c])
// ======================================================================
__global__ void k_bases_t(const float* __restrict__ bases, __bf16* __restrict__ Bt,
                          int din, int dout) {
    int idx = blockIdx.x*256 + threadIdx.x;
    int tot = NBAS*din*dout;
    if (idx >= tot) return;
    int b = idx/(dout*din), rem = idx%(dout*din);
    int c = rem/din, k = rem%din;
    Bt[idx] = (__bf16)bases[((size_t)b*din + k)*dout + c];
}
__global__ void k_loop_t(const float* __restrict__ loopw, __bf16* __restrict__ loopt,
                         int din, int dout) {
    int idx = blockIdx.x*256 + threadIdx.x;
    if (idx >= din*dout) return;
    int c = idx/din, k = idx%din;
    loopt[idx] = (__bf16)loopw[(size_t)k*dout + c];
}
// features f32 -> bf16 (one streaming pass; halves L0 gather line-misses)
__global__ void k_feat2bf(const float* __restrict__ f, __bf16* __restrict__ fb) {
    int i = blockIdx.x*256 + threadIdx.x;   // processes 8 elems
    if (i >= N_NODES*C_IN/8) return;
    const float4* p = (const float4*)(f + (size_t)i*8);
    float4 a = p[0], b = p[1];
    bf16x8 o;
    o[0]=(__bf16)a.x; o[1]=(__bf16)a.y; o[2]=(__bf16)a.z; o[3]=(__bf16)a.w;
    o[4]=(__bf16)b.x; o[5]=(__bf16)b.y; o[6]=(__bf16)b.z; o[7]=(__bf16)b.w;
    *(bf16x8*)(fb + (size_t)i*8) = o;
}

// ======================================================================
// prep: plain dst-CSR, single scatter with fused 8B metadata per edge:
//   pmeta[j] = { src | et<<24 , bits(norm) }
// ======================================================================
__global__ void k_deg(const int* __restrict__ dst, int* __restrict__ deg) {
    int e = blockIdx.x*256 + threadIdx.x;
    if (e < E_EDGES) atomicAdd(&deg[dst[e]], 1);
}
__global__ __launch_bounds__(256) void k_scan1(const int* __restrict__ deg,
                                               int* __restrict__ rowptr,
                                               int* __restrict__ bsum) {
    __shared__ int s[256], s2[256];
    const int tid = threadIdx.x, gid = blockIdx.x*256 + tid;
    int v = deg[gid];
    s[tid] = v;
    __syncthreads();
    int* cur = s; int* nxt = s2;
    for (int d = 1; d < 256; d <<= 1) {
        int val = cur[tid];
        if (tid >= d) val += cur[tid - d];
        nxt[tid] = val;
        __syncthreads();
        int* t = cur; cur = nxt; nxt = t;
    }
    rowptr[gid] = cur[tid] - v;
    if (tid == 255) bsum[blockIdx.x] = cur[255];
}
__global__ __launch_bounds__(512) void k_scan2(int* __restrict__ bsum, int* __restrict__ rowptr) {
    __shared__ int s[512], s2[512];
    const int tid = threadIdx.x;
    int v = (tid < SCAN_BLOCKS) ? bsum[tid] : 0;
    s[tid] = v;
    __syncthreads();
    int* cur = s; int* nxt = s2;
    for (int d = 1; d < 512; d <<= 1) {
        int val = cur[tid];
        if (tid >= d) val += cur[tid - d];
        nxt[tid] = val;
        __syncthreads();
        int* t = cur; cur = nxt; nxt = t;
    }
    if (tid < SCAN_BLOCKS) bsum[tid] = cur[tid] - v;   // exclusive
    if (tid == 0) rowptr[N_NODES] = E_EDGES;
}
__global__ void k_scan3(int* __restrict__ rowptr, const int* __restrict__ bsum,
                        int* __restrict__ cursor) {
    int gid = blockIdx.x*256 + threadIdx.x;
    int v = rowptr[gid] + bsum[blockIdx.x];
    rowptr[gid] = v;
    cursor[gid] = v;
}
__global__ void k_scatter_pack(const int* __restrict__ src, const int* __restrict__ dst,
                               const int* __restrict__ et, const float* __restrict__ norm,
                               int* __restrict__ cursor, int2* __restrict__ pmeta) {
    int e = blockIdx.x*256 + threadIdx.x;
    if (e < E_EDGES) {
        int pos = atomicAdd(&cursor[dst[e]], 1);
        int2 m;
        m.x = src[e] | (et[e] << 24);
        m.y = __float_as_int(norm[e]);
        pmeta[pos] = m;
    }
}

// ======================================================================
// Fused basis RGCN layer (R13 structure — best measured):
//   hout[n] = act( sum_b (sum_e norm*comp[et,b]*h[src]) @ B_b + h[n]@loopw + bias )
// Single-pass gather, meta prefetch 1 ahead, 4 basis MFMA phases + self-loop.
// Lane l: m=l&15 (row), g=l>>4 (K-subgroup). D: row g*4+ri, col nf*16+m.
// ======================================================================
template<int DIN, int DOUT, int ACT, int IN_F32, int OUT_F32, int MINW>
__global__ __launch_bounds__(256, MINW) void k_fusedb(
        const void* __restrict__ hin, const __bf16* __restrict__ Bt,
        const __bf16* __restrict__ loopt, const float* __restrict__ bias,
        const float* __restrict__ comp, const int* __restrict__ rowptr,
        const int2* __restrict__ pmeta, void* __restrict__ hout) {
    constexpr int KS = DIN/32;
    constexpr int NF = DOUT/16;
    const int tid = threadIdx.x;
    const int w = tid >> 6, l = tid & 63;
    const int m = l & 15, g = l >> 4;
    const int nb = blockIdx.x*64 + w*16;
    const int node = nb + m;

    f32x4 acc[NF];
    #pragma unroll
    for (int nf = 0; nf < NF; ++nf) acc[nf] = (f32x4){0.f,0.f,0.f,0.f};

    float ka[NBAS][KS][8];
    #pragma unroll
    for (int b = 0; b < NBAS; ++b)
        #pragma unroll
        for (int ks = 0; ks < KS; ++ks)
            #pragma unroll
            for (int c = 0; c < 8; ++c) ka[b][ks][c] = 0.f;

    const int jb = rowptr[node], je = rowptr[node+1];
    int2 mt = pmeta[jb];                 // safe: pmeta padded
    for (int j = jb; j < je; ++j) {
        const int2 mtn = pmeta[j+1];     // prefetch next
        const int p = mt.x & 0xFFFFFF;
        const int et = ((unsigned)mt.x) >> 24;
        const float nm = __int_as_float(mt.y);
        const float4 cw = *(const float4*)(comp + et*NBAS);
        const float w0 = nm*cw.x, w1 = nm*cw.y, w2 = nm*cw.z, w3 = nm*cw.w;
        float hv[KS][8];
        if (IN_F32) {
            const float* hp = (const float*)hin + (size_t)p*DIN + g*8;
            #pragma unroll
            for (int ks = 0; ks < KS; ++ks) {
                float4 v0 = *(const float4*)(hp + ks*32);
                float4 v1 = *(const float4*)(hp + ks*32 + 4);
                hv[ks][0]=v0.x; hv[ks][1]=v0.y; hv[ks][2]=v0.z; hv[ks][3]=v0.w;
                hv[ks][4]=v1.x; hv[ks][5]=v1.y; hv[ks][6]=v1.z; hv[ks][7]=v1.w;
            }
        } else {
            const __bf16* hp = (const __bf16*)hin + (size_t)p*DIN + g*8;
            #pragma unroll
            for (int ks = 0; ks < KS; ++ks) {
                bf16x8 v = *(const bf16x8*)(hp + ks*32);
                #pragma unroll
                for (int c = 0; c < 8; ++c) hv[ks][c] = (float)v[c];
            }
        }
        #pragma unroll
        for (int ks = 0; ks < KS; ++ks) {
            #pragma unroll
            for (int c = 0; c < 8; ++c) {
                ka[0][ks][c] += w0*hv[ks][c];
                ka[1][ks][c] += w1*hv[ks][c];
                ka[2][ks][c] += w2*hv[ks][c];
                ka[3][ks][c] += w3*hv[ks][c];
            }
        }
        mt = mtn;
    }

    #pragma unroll
    for (int b = 0; b < NBAS; ++b) {
        #pragma unroll
        for (int ks = 0; ks < KS; ++ks) {
            bf16x8 fa;
            #pragma unroll
            for (int c = 0; c < 8; ++c) fa[c] = (__bf16)ka[b][ks][c];
            #pragma unroll
            for (int nf = 0; nf < NF; ++nf) {
                bf16x8 fb = *(const bf16x8*)(Bt + ((size_t)b*DOUT + nf*16 + m)*DIN
                                             + ks*32 + g*8);
                acc[nf] = __builtin_amdgcn_mfma_f32_16x16x32_bf16(fa, fb, acc[nf], 0, 0, 0);
            }
        }
    }

    #pragma unroll
    for (int ks = 0; ks < KS; ++ks) {
        bf16x8 fa;
        if (IN_F32) {
            const float* hp = (const float*)hin + (size_t)node*DIN + ks*32 + g*8;
            float4 v0 = *(const float4*)hp;
            float4 v1 = *(const float4*)(hp + 4);
            fa[0]=(__bf16)v0.x; fa[1]=(__bf16)v0.y; fa[2]=(__bf16)v0.z; fa[3]=(__bf16)v0.w;
            fa[4]=(__bf16)v1.x; fa[5]=(__bf16)v1.y; fa[6]=(__bf16)v1.z; fa[7]=(__bf16)v1.w;
        } else {
            fa = *(const bf16x8*)((const __bf16*)hin + (size_t)node*DIN + ks*32 + g*8);
        }
        #pragma unroll
        for (int nf = 0; nf < NF; ++nf) {
            bf16x8 fb = *(const bf16x8*)(loopt + (size_t)(nf*16 + m)*DIN + ks*32 + g*8);
            acc[nf] = __builtin_amdgcn_mfma_f32_16x16x32_bf16(fa, fb, acc[nf], 0, 0, 0);
        }
    }

    #pragma unroll
    for (int nf = 0; nf < NF; ++nf) {
        const int col = nf*16 + m;
        const float bv = bias[col];
        #pragma unroll
        for (int ri = 0; ri < 4; ++ri) {
            const int orow = nb + g*4 + ri;
            float v = acc[nf][ri] + bv;
            if (ACT == 0) v = (v >= 0.f) ? v : NEG_SLOPE*v;
            else          v = 1.f/(1.f + __expf(-v));
            if (OUT_F32) ((float*)hout)[(size_t)orow*DOUT + col] = v;
            else         ((__bf16*)hout)[(size_t)orow*DOUT + col] = (__bf16)v;
        }
    }
}

// ======================================================================
// Phase-blocked conv-transpose decoder + sigmoid.
// Outputs with the same phase (py,px) = ((oy+2)%3,(ox+2)%3) share <=9 taps.
// Thread computes a 3x3 same-phase output block (qy0..+2, qx0..+2):
// each input-cell quad feeds up to 9 FMAs, each weight quad 9 FMAs
// -> loads cut ~2.5-4x vs output-major. Block = one phase (uniform bounds).
// oy = 3*qy+py-2, tap ky = py+3*sy, cell iy = qy-sy.
// ======================================================================
__global__ __launch_bounds__(256, 3) void k_convt_ph(const float* __restrict__ logits,
        const float* __restrict__ w, const float* __restrict__ cb, float* __restrict__ out) {
    __shared__ float s_w[49*32];   // [tap][c]
    const int tid = threadIdx.x;
    for (int idx = tid; idx < 49*32; idx += 256) {
        int tap = idx/32, c = idx%32;
        s_w[tap*32 + c] = w[c*49 + tap];
    }
    __syncthreads();

    const int phase = blockIdx.y;
    const int py = phase/3, px = phase%3;
    const int SY = (py == 0) ? 3 : 2;     // valid sy count (ky = py+3sy <= 6)
    const int SX = (px == 0) ? 3 : 2;
    const int qylo = (py == 2) ? 0 : 1;   // qy range start (30 values)
    const int qxlo = (px == 2) ? 0 : 1;

    const int idx = blockIdx.x*256 + tid;          // < 12800
    const int b = idx/100, r = idx%100;
    const int qy0 = qylo + (r/10)*3;
    const int qx0 = qxlo + (r%10)*3;

    const float cb0 = cb[0];
    float acc[3][3];
    #pragma unroll
    for (int ry = 0; ry < 3; ++ry)
        #pragma unroll
        for (int rx = 0; rx < 3; ++rx) acc[ry][rx] = cb0;

    for (int c4 = 0; c4 < 8; ++c4) {
        // weight quads for this phase's taps
        float4 wq[3][3];
        #pragma unroll
        for (int sy = 0; sy < 3; ++sy) {
            if (sy < SY) {
                #pragma unroll
                for (int sx = 0; sx < 3; ++sx) {
                    if (sx < SX)
                        wq[sy][sx] = *(const float4*)&s_w[((py+3*sy)*7 + px+3*sx)*32 + c4*4];
                }
            }
        }
        // cell quads: cq[dy][dx] = cell (qy0+2-dy, qx0+2-dx)
        float4 cq[5][5];
        #pragma unroll
        for (int dy = 0; dy < 5; ++dy) {
            if (dy < SY + 2) {
                const int iy = qy0 + 2 - dy;
                #pragma unroll
                for (int dx = 0; dx < 5; ++dx) {
                    if (dx < SX + 2) {
                        const int ix = qx0 + 2 - dx;
                        if (iy >= 0 && iy < GWID && ix >= 0 && ix < GWID)
                            cq[dy][dx] = *(const float4*)&logits[(((size_t)b*GWID + iy)*GWID + ix)*32 + c4*4];
                        else
                            cq[dy][dx] = make_float4(0.f,0.f,0.f,0.f);
                    }
                }
            }
        }
        // fma: output (ry,rx) tap (sy,sx) uses cell dy = 2-ry+sy, dx = 2-rx+sx
        #pragma unroll
        for (int sy = 0; sy < 3; ++sy) {
            if (sy < SY) {
                #pragma unroll
                for (int sx = 0; sx < 3; ++sx) {
                    if (sx < SX) {
                        const float4 wv = wq[sy][sx];
                        #pragma unroll
                        for (int ry = 0; ry < 3; ++ry) {
                            #pragma unroll
                            for (int rx = 0; rx < 3; ++rx) {
                                const float4 xv = cq[2-ry+sy][2-rx+sx];
                                acc[ry][rx] += xv.x*wv.x + xv.y*wv.y + xv.z*wv.z + xv.w*wv.w;
                            }
                        }
                    }
                }
            }
        }
    }

    // epilogue: sigmoid + store (oy,ox always in-range by construction)
    #pragma unroll
    for (int ry = 0; ry < 3; ++ry) {
        const int oy = 3*(qy0 + ry) + py - 2;
        #pragma unroll
        for (int rx = 0; rx < 3; ++rx) {
            const int ox = 3*(qx0 + rx) + px - 2;
            out[((size_t)b*IWID + oy)*IWID + ox] = 1.f/(1.f + __expf(-acc[ry][rx]));
        }
    }
}

// ======================================================================
// host
// ======================================================================
extern "C" void kernel_launch(void* const* d_in, const int* in_sizes, int n_in,
                              void* d_out, int out_size, void* d_ws, size_t ws_size,
                              hipStream_t stream) {
    const float* features = (const float*)d_in[0];
    const int*   src      = (const int*)  d_in[1];
    const int*   dst      = (const int*)  d_in[2];
    const int*   etypes   = (const int*)  d_in[3];
    const float* norm     = (const float*)d_in[4];
    const float* bases0 = (const float*)d_in[5];
    const float* comp0  = (const float*)d_in[6];
    const float* loop0  = (const float*)d_in[7];
    const float* bias0  = (const float*)d_in[8];
    const float* bases1 = (const float*)d_in[9];
    const float* comp1  = (const float*)d_in[10];
    const float* loop1  = (const float*)d_in[11];
    const float* bias1  = (const float*)d_in[12];
    const float* bases2 = (const float*)d_in[13];
    const float* comp2  = (const float*)d_in[14];
    const float* loop2  = (const float*)d_in[15];
    const float* bias2  = (const float*)d_in[16];
    const float* conv_w = (const float*)d_in[17];
    const float* conv_b = (const float*)d_in[18];
    float* out = (float*)d_out;

    const int ebl = (E_EDGES + 255)/256;
    float* ws = (float*)d_ws;
    auto pad4 = [](size_t v){ return (v + 3) & ~(size_t)3; };

    // ---- workspace carve (float units), total ~60 MB ----
    size_t off = 0;
    __bf16* Bt0   = (__bf16*)(ws + off); off += (size_t)NBAS*32*64/2;
    __bf16* Bt1   = (__bf16*)(ws + off); off += (size_t)NBAS*64*64/2;
    __bf16* Bt2   = (__bf16*)(ws + off); off += (size_t)NBAS*64*32/2;
    __bf16* lt0   = (__bf16*)(ws + off); off += (size_t)64*32/2;
    __bf16* lt1   = (__bf16*)(ws + off); off += (size_t)64*64/2;
    __bf16* lt2   = (__bf16*)(ws + off); off += (size_t)32*64/2;
    __bf16* fbf   = (__bf16*)(ws + off); off += (size_t)N_NODES*C_IN/2;   // bf16 features
    __bf16* h1    = (__bf16*)(ws + off); off += (size_t)N_NODES*64/2;
    __bf16* h2    = (__bf16*)(ws + off); off += (size_t)N_NODES*64/2;
    float*  lg    = (float*)(ws + off);  off += (size_t)N_NODES*32;   // f32 logits
    int* rowptr   = (int*)(ws + off); off += pad4((size_t)N_NODES + 4);
    int* deg      = (int*)(ws + off); off += (size_t)N_NODES;   // becomes cursor
    int* bsum     = (int*)(ws + off); off += 512;
    int2* pmeta   = (int2*)(ws + off); off += (size_t)(E_EDGES + 8)*2;  // +8 pad

    // ---- weight prep (transposed bf16 basis + loop tables) + feature cvt ----
    k_bases_t<<<(NBAS*32*64 + 255)/256, 256, 0, stream>>>(bases0, Bt0, 32, 64);
    k_bases_t<<<(NBAS*64*64 + 255)/256, 256, 0, stream>>>(bases1, Bt1, 64, 64);
    k_bases_t<<<(NBAS*64*32 + 255)/256, 256, 0, stream>>>(bases2, Bt2, 64, 32);
    k_loop_t<<<(32*64 + 255)/256, 256, 0, stream>>>(loop0, lt0, 32, 64);
    k_loop_t<<<(64*64 + 255)/256, 256, 0, stream>>>(loop1, lt1, 64, 64);
    k_loop_t<<<(64*32 + 255)/256, 256, 0, stream>>>(loop2, lt2, 64, 32);
    k_feat2bf<<<(N_NODES*C_IN/8 + 255)/256, 256, 0, stream>>>(features, fbf);

    // ---- dst-CSR + single packed scatter (reused by all 3 layers) ----
    hipMemsetAsync(deg, 0, (size_t)N_NODES*sizeof(int), stream);
    k_deg  <<<ebl, 256, 0, stream>>>(dst, deg);
    k_scan1<<<SCAN_BLOCKS, 256, 0, stream>>>(deg, rowptr, bsum);
    k_scan2<<<1, 512, 0, stream>>>(bsum, rowptr);
    k_scan3<<<SCAN_BLOCKS, 256, 0, stream>>>(rowptr, bsum, deg);
    k_scatter_pack<<<ebl, 256, 0, stream>>>(src, dst, etypes, norm, deg, pmeta);

    const int NROWT = N_NODES/64;   // 1800

    // ---- 3 fused basis layers (R13 structure; L0 reads bf16 features) ----
    k_fusedb<32,64,0,0,0,4><<<NROWT, 256, 0, stream>>>(fbf, Bt0, lt0, bias0, comp0,
                                                       rowptr, pmeta, h1);
    k_fusedb<64,64,0,0,0,3><<<NROWT, 256, 0, stream>>>(h1, Bt1, lt1, bias1, comp1,
                                                       rowptr, pmeta, h2);
    k_fusedb<64,32,1,0,1,3><<<NROWT, 256, 0, stream>>>(h2, Bt2, lt2, bias2, comp2,
                                                       rowptr, pmeta, lg);

    // ---- decoder: phase-blocked 3x3 register-tiled conv-transpose ----
    k_convt_ph<<<dim3(50, 9), 256, 0, stream>>>(lg, conv_w, conv_b, out);
}

// Round 21
// 331.203 us; speedup vs baseline: 1.5485x; 1.5485x over previous
//
#include <hip/hip_runtime.h>
#include <hip/hip_bf16.h>

// Problem constants (match reference)
#define B_GR   128
#define GWID   30
#define IWID   90
#define C_IN   32
#define R_REL  8
#define NBAS   4
#define N_NODES (B_GR*GWID*GWID)   // 115200
#define E_EDGES (N_NODES*8)        // 921600
#define NEG_SLOPE 0.01f

#define SCAN_BLOCKS (N_NODES/256)  // 450

typedef __attribute__((ext_vector_type(8))) __bf16 bf16x8;
typedef __attribute__((ext_vector_type(4))) float f32x4;

// ======================================================================
// Weight prep: Bt[b][c][k] = bf16(bases[b][k][c])  (B^T per base)
//              loopt[c][k] = bf16(loopw[k][c])
// ======================================================================
__global__ void k_bases_t(const float* __restrict__ bases, __bf16* __restrict__ Bt,
                          int din, int dout) {
    int idx = blockIdx.x*256 + threadIdx.x;
    int tot = NBAS*din*dout;
    if (idx >= tot) return;
    int b = idx/(dout*din), rem = idx%(dout*din);
    int c = rem/din, k = rem%din;
    Bt[idx] = (__bf16)bases[((size_t)b*din + k)*dout + c];
}
__global__ void k_loop_t(const float* __restrict__ loopw, __bf16* __restrict__ loopt,
                         int din, int dout) {
    int idx = blockIdx.x*256 + threadIdx.x;
    if (idx >= din*dout) return;
    int c = idx/din, k = idx%din;
    loopt[idx] = (__bf16)loopw[(size_t)k*dout + c];
}
// features f32 -> bf16 (one streaming pass; halves L0 gather line-misses)
__global__ void k_feat2bf(const float* __restrict__ f, __bf16* __restrict__ fb) {
    int i = blockIdx.x*256 + threadIdx.x;   // processes 8 elems
    if (i >= N_NODES*C_IN/8) return;
    const float4* p = (const float4*)(f + (size_t)i*8);
    float4 a = p[0], b = p[1];
    bf16x8 o;
    o[0]=(__bf16)a.x; o[1]=(__bf16)a.y; o[2]=(__bf16)a.z; o[3]=(__bf16)a.w;
    o[4]=(__bf16)b.x; o[5]=(__bf16)b.y; o[6]=(__bf16)b.z; o[7]=(__bf16)b.w;
    *(bf16x8*)(fb + (size_t)i*8) = o;
}

// ======================================================================
// prep: plain dst-CSR, single scatter with fused 8B metadata per edge:
//   pmeta[j] = { src | et<<24 , bits(norm) }
// ======================================================================
__global__ void k_deg(const int* __restrict__ dst, int* __restrict__ deg) {
    int e = blockIdx.x*256 + threadIdx.x;
    if (e < E_EDGES) atomicAdd(&deg[dst[e]], 1);
}
__global__ __launch_bounds__(256) void k_scan1(const int* __restrict__ deg,
                                               int* __restrict__ rowptr,
                                               int* __restrict__ bsum) {
    __shared__ int s[256], s2[256];
    const int tid = threadIdx.x, gid = blockIdx.x*256 + tid;
    int v = deg[gid];
    s[tid] = v;
    __syncthreads();
    int* cur = s; int* nxt = s2;
    for (int d = 1; d < 256; d <<= 1) {
        int val = cur[tid];
        if (tid >= d) val += cur[tid - d];
        nxt[tid] = val;
        __syncthreads();
        int* t = cur; cur = nxt; nxt = t;
    }
    rowptr[gid] = cur[tid] - v;
    if (tid == 255) bsum[blockIdx.x] = cur[255];
}
__global__ __launch_bounds__(512) void k_scan2(int* __restrict__ bsum, int* __restrict__ rowptr) {
    __shared__ int s[512], s2[512];
    const int tid = threadIdx.x;
    int v = (tid < SCAN_BLOCKS) ? bsum[tid] : 0;
    s[tid] = v;
    __syncthreads();
    int* cur = s; int* nxt = s2;
    for (int d = 1; d < 512; d <<= 1) {
        int val = cur[tid];
        if (tid >= d) val += cur[tid - d];
        nxt[tid] = val;
        __syncthreads();
        int* t = cur; cur = nxt; nxt = t;
    }
    if (tid < SCAN_BLOCKS) bsum[tid] = cur[tid] - v;   // exclusive
    if (tid == 0) rowptr[N_NODES] = E_EDGES;
}
__global__ void k_scan3(int* __restrict__ rowptr, const int* __restrict__ bsum,
                        int* __restrict__ cursor) {
    int gid = blockIdx.x*256 + threadIdx.x;
    int v = rowptr[gid] + bsum[blockIdx.x];
    rowptr[gid] = v;
    cursor[gid] = v;
}
__global__ void k_scatter_pack(const int* __restrict__ src, const int* __restrict__ dst,
                               const int* __restrict__ et, const float* __restrict__ norm,
                               int* __restrict__ cursor, int2* __restrict__ pmeta) {
    int e = blockIdx.x*256 + threadIdx.x;
    if (e < E_EDGES) {
        int pos = atomicAdd(&cursor[dst[e]], 1);
        int2 m;
        m.x = src[e] | (et[e] << 24);
        m.y = __float_as_int(norm[e]);
        pmeta[pos] = m;
    }
}

// ======================================================================
// Fused basis RGCN layer (R13 structure — best measured):
//   hout[n] = act( sum_b (sum_e norm*comp[et,b]*h[src]) @ B_b + h[n]@loopw + bias )
// Single-pass gather, meta prefetch 1 ahead, 4 basis MFMA phases + self-loop.
// Lane l: m=l&15 (row), g=l>>4 (K-subgroup). D: row g*4+ri, col nf*16+m.
// ======================================================================
template<int DIN, int DOUT, int ACT, int IN_F32, int OUT_F32, int MINW>
__global__ __launch_bounds__(256, MINW) void k_fusedb(
        const void* __restrict__ hin, const __bf16* __restrict__ Bt,
        const __bf16* __restrict__ loopt, const float* __restrict__ bias,
        const float* __restrict__ comp, const int* __restrict__ rowptr,
        const int2* __restrict__ pmeta, void* __restrict__ hout) {
    constexpr int KS = DIN/32;
    constexpr int NF = DOUT/16;
    const int tid = threadIdx.x;
    const int w = tid >> 6, l = tid & 63;
    const int m = l & 15, g = l >> 4;
    const int nb = blockIdx.x*64 + w*16;
    const int node = nb + m;

    f32x4 acc[NF];
    #pragma unroll
    for (int nf = 0; nf < NF; ++nf) acc[nf] = (f32x4){0.f,0.f,0.f,0.f};

    float ka[NBAS][KS][8];
    #pragma unroll
    for (int b = 0; b < NBAS; ++b)
        #pragma unroll
        for (int ks = 0; ks < KS; ++ks)
            #pragma unroll
            for (int c = 0; c < 8; ++c) ka[b][ks][c] = 0.f;

    const int jb = rowptr[node], je = rowptr[node+1];
    int2 mt = pmeta[jb];                 // safe: pmeta padded
    for (int j = jb; j < je; ++j) {
        const int2 mtn = pmeta[j+1];     // prefetch next
        const int p = mt.x & 0xFFFFFF;
        const int et = ((unsigned)mt.x) >> 24;
        const float nm = __int_as_float(mt.y);
        const float4 cw = *(const float4*)(comp + et*NBAS);
        const float w0 = nm*cw.x, w1 = nm*cw.y, w2 = nm*cw.z, w3 = nm*cw.w;
        float hv[KS][8];
        if (IN_F32) {
            const float* hp = (const float*)hin + (size_t)p*DIN + g*8;
            #pragma unroll
            for (int ks = 0; ks < KS; ++ks) {
                float4 v0 = *(const float4*)(hp + ks*32);
                float4 v1 = *(const float4*)(hp + ks*32 + 4);
                hv[ks][0]=v0.x; hv[ks][1]=v0.y; hv[ks][2]=v0.z; hv[ks][3]=v0.w;
                hv[ks][4]=v1.x; hv[ks][5]=v1.y; hv[ks][6]=v1.z; hv[ks][7]=v1.w;
            }
        } else {
            const __bf16* hp = (const __bf16*)hin + (size_t)p*DIN + g*8;
            #pragma unroll
            for (int ks = 0; ks < KS; ++ks) {
                bf16x8 v = *(const bf16x8*)(hp + ks*32);
                #pragma unroll
                for (int c = 0; c < 8; ++c) hv[ks][c] = (float)v[c];
            }
        }
        #pragma unroll
        for (int ks = 0; ks < KS; ++ks) {
            #pragma unroll
            for (int c = 0; c < 8; ++c) {
                ka[0][ks][c] += w0*hv[ks][c];
                ka[1][ks][c] += w1*hv[ks][c];
                ka[2][ks][c] += w2*hv[ks][c];
                ka[3][ks][c] += w3*hv[ks][c];
            }
        }
        mt = mtn;
    }

    #pragma unroll
    for (int b = 0; b < NBAS; ++b) {
        #pragma unroll
        for (int ks = 0; ks < KS; ++ks) {
            bf16x8 fa;
            #pragma unroll
            for (int c = 0; c < 8; ++c) fa[c] = (__bf16)ka[b][ks][c];
            #pragma unroll
            for (int nf = 0; nf < NF; ++nf) {
                bf16x8 fb = *(const bf16x8*)(Bt + ((size_t)b*DOUT + nf*16 + m)*DIN
                                             + ks*32 + g*8);
                acc[nf] = __builtin_amdgcn_mfma_f32_16x16x32_bf16(fa, fb, acc[nf], 0, 0, 0);
            }
        }
    }

    #pragma unroll
    for (int ks = 0; ks < KS; ++ks) {
        bf16x8 fa;
        if (IN_F32) {
            const float* hp = (const float*)hin + (size_t)node*DIN + ks*32 + g*8;
            float4 v0 = *(const float4*)hp;
            float4 v1 = *(const float4*)(hp + 4);
            fa[0]=(__bf16)v0.x; fa[1]=(__bf16)v0.y; fa[2]=(__bf16)v0.z; fa[3]=(__bf16)v0.w;
            fa[4]=(__bf16)v1.x; fa[5]=(__bf16)v1.y; fa[6]=(__bf16)v1.z; fa[7]=(__bf16)v1.w;
        } else {
            fa = *(const bf16x8*)((const __bf16*)hin + (size_t)node*DIN + ks*32 + g*8);
        }
        #pragma unroll
        for (int nf = 0; nf < NF; ++nf) {
            bf16x8 fb = *(const bf16x8*)(loopt + (size_t)(nf*16 + m)*DIN + ks*32 + g*8);
            acc[nf] = __builtin_amdgcn_mfma_f32_16x16x32_bf16(fa, fb, acc[nf], 0, 0, 0);
        }
    }

    #pragma unroll
    for (int nf = 0; nf < NF; ++nf) {
        const int col = nf*16 + m;
        const float bv = bias[col];
        #pragma unroll
        for (int ri = 0; ri < 4; ++ri) {
            const int orow = nb + g*4 + ri;
            float v = acc[nf][ri] + bv;
            if (ACT == 0) v = (v >= 0.f) ? v : NEG_SLOPE*v;
            else          v = 1.f/(1.f + __expf(-v));
            if (OUT_F32) ((float*)hout)[(size_t)orow*DOUT + col] = v;
            else         ((__bf16*)hout)[(size_t)orow*DOUT + col] = (__bf16)v;
        }
    }
}

// ======================================================================
// conv-transpose decoder + sigmoid, f32 logits, branchless phase taps.
// (output-major: adjacent lanes share input rows in L1 — keeps coalescing)
// ======================================================================
__global__ __launch_bounds__(256) void k_convt_f32(const float* __restrict__ logits,
        const float* __restrict__ w, const float* __restrict__ cb, float* __restrict__ out) {
    __shared__ float s_w[49*32];   // [tap][c]
    const int tid = threadIdx.x;
    for (int idx = tid; idx < 49*32; idx += 256) {
        int tap = idx/32, c = idx%32;
        s_w[tap*32 + c] = w[c*49 + tap];
    }
    __syncthreads();
    int gidx = blockIdx.x*256 + tid;
    if (gidx >= B_GR*IWID*IWID) return;
    int b = gidx/(IWID*IWID);
    int rem = gidx%(IWID*IWID);
    int oy = rem/IWID, ox = rem%IWID;

    const int py = (oy+2)%3, qy = (oy+2)/3;
    const int px = (ox+2)%3, qx = (ox+2)/3;

    float acc = cb[0];
    #pragma unroll
    for (int sy = 0; sy < 3; ++sy) {
        const int ky = py + 3*sy;
        const int iy = qy - sy;
        if (ky > 6 || iy < 0 || iy >= GWID) continue;
        #pragma unroll
        for (int sx = 0; sx < 3; ++sx) {
            const int kx = px + 3*sx;
            const int ix = qx - sx;
            if (kx > 6 || ix < 0 || ix >= GWID) continue;
            const float4* xp = (const float4*)&logits[(((size_t)b*GWID + iy)*GWID + ix)*32];
            const float4* wp = (const float4*)&s_w[(ky*7 + kx)*32];
            #pragma unroll
            for (int c4 = 0; c4 < 8; ++c4) {
                float4 xv = xp[c4], wv = wp[c4];
                acc += xv.x*wv.x + xv.y*wv.y + xv.z*wv.z + xv.w*wv.w;
            }
        }
    }
    out[gidx] = 1.f/(1.f + __expf(-acc));
}

// ======================================================================
// host
// ======================================================================
extern "C" void kernel_launch(void* const* d_in, const int* in_sizes, int n_in,
                              void* d_out, int out_size, void* d_ws, size_t ws_size,
                              hipStream_t stream) {
    const float* features = (const float*)d_in[0];
    const int*   src      = (const int*)  d_in[1];
    const int*   dst      = (const int*)  d_in[2];
    const int*   etypes   = (const int*)  d_in[3];
    const float* norm     = (const float*)d_in[4];
    const float* bases0 = (const float*)d_in[5];
    const float* comp0  = (const float*)d_in[6];
    const float* loop0  = (const float*)d_in[7];
    const float* bias0  = (const float*)d_in[8];
    const float* bases1 = (const float*)d_in[9];
    const float* comp1  = (const float*)d_in[10];
    const float* loop1  = (const float*)d_in[11];
    const float* bias1  = (const float*)d_in[12];
    const float* bases2 = (const float*)d_in[13];
    const float* comp2  = (const float*)d_in[14];
    const float* loop2  = (const float*)d_in[15];
    const float* bias2  = (const float*)d_in[16];
    const float* conv_w = (const float*)d_in[17];
    const float* conv_b = (const float*)d_in[18];
    float* out = (float*)d_out;

    const int ebl = (E_EDGES + 255)/256;
    float* ws = (float*)d_ws;
    auto pad4 = [](size_t v){ return (v + 3) & ~(size_t)3; };

    // ---- workspace carve (float units), total ~60 MB ----
    size_t off = 0;
    __bf16* Bt0   = (__bf16*)(ws + off); off += (size_t)NBAS*32*64/2;
    __bf16* Bt1   = (__bf16*)(ws + off); off += (size_t)NBAS*64*64/2;
    __bf16* Bt2   = (__bf16*)(ws + off); off += (size_t)NBAS*64*32/2;
    __bf16* lt0   = (__bf16*)(ws + off); off += (size_t)64*32/2;
    __bf16* lt1   = (__bf16*)(ws + off); off += (size_t)64*64/2;
    __bf16* lt2   = (__bf16*)(ws + off); off += (size_t)32*64/2;
    __bf16* fbf   = (__bf16*)(ws + off); off += (size_t)N_NODES*C_IN/2;   // bf16 features
    __bf16* h1    = (__bf16*)(ws + off); off += (size_t)N_NODES*64/2;
    __bf16* h2    = (__bf16*)(ws + off); off += (size_t)N_NODES*64/2;
    float*  lg    = (float*)(ws + off);  off += (size_t)N_NODES*32;   // f32 logits
    int* rowptr   = (int*)(ws + off); off += pad4((size_t)N_NODES + 4);
    int* deg      = (int*)(ws + off); off += (size_t)N_NODES;   // becomes cursor
    int* bsum     = (int*)(ws + off); off += 512;
    int2* pmeta   = (int2*)(ws + off); off += (size_t)(E_EDGES + 8)*2;  // +8 pad

    // ---- weight prep (transposed bf16 basis + loop tables) + feature cvt ----
    k_bases_t<<<(NBAS*32*64 + 255)/256, 256, 0, stream>>>(bases0, Bt0, 32, 64);
    k_bases_t<<<(NBAS*64*64 + 255)/256, 256, 0, stream>>>(bases1, Bt1, 64, 64);
    k_bases_t<<<(NBAS*64*32 + 255)/256, 256, 0, stream>>>(bases2, Bt2, 64, 32);
    k_loop_t<<<(32*64 + 255)/256, 256, 0, stream>>>(loop0, lt0, 32, 64);
    k_loop_t<<<(64*64 + 255)/256, 256, 0, stream>>>(loop1, lt1, 64, 64);
    k_loop_t<<<(64*32 + 255)/256, 256, 0, stream>>>(loop2, lt2, 64, 32);
    k_feat2bf<<<(N_NODES*C_IN/8 + 255)/256, 256, 0, stream>>>(features, fbf);

    // ---- dst-CSR + single packed scatter (reused by all 3 layers) ----
    hipMemsetAsync(deg, 0, (size_t)N_NODES*sizeof(int), stream);
    k_deg  <<<ebl, 256, 0, stream>>>(dst, deg);
    k_scan1<<<SCAN_BLOCKS, 256, 0, stream>>>(deg, rowptr, bsum);
    k_scan2<<<1, 512, 0, stream>>>(bsum, rowptr);
    k_scan3<<<SCAN_BLOCKS, 256, 0, stream>>>(rowptr, bsum, deg);
    k_scatter_pack<<<ebl, 256, 0, stream>>>(src, dst, etypes, norm, deg, pmeta);

    const int NROWT = N_NODES/64;   // 1800

    // ---- 3 fused basis layers (R13 structure; L0 reads bf16 features) ----
    k_fusedb<32,64,0,0,0,4><<<NROWT, 256, 0, stream>>>(fbf, Bt0, lt0, bias0, comp0,
                                                       rowptr, pmeta, h1);
    k_fusedb<64,64,0,0,0,3><<<NROWT, 256, 0, stream>>>(h1, Bt1, lt1, bias1, comp1,
                                                       rowptr, pmeta, h2);
    k_fusedb<64,32,1,0,1,3><<<NROWT, 256, 0, stream>>>(h2, Bt2, lt2, bias2, comp2,
                                                       rowptr, pmeta, lg);

    // ---- decoder (f32 logits, output-major = coalesced) ----
    k_convt_f32<<<(B_GR*IWID*IWID + 255)/256, 256, 0, stream>>>(lg, conv_w, conv_b, out);
}